// Round 16
// baseline (107.299 us; speedup 1.0000x reference)
//
#include <hip/hip_runtime.h>
#include <stdint.h>

// OSTL spiking-LIF forward.
// R14: ONE variable vs R13: GEMM occupancy. BN 128->64, grid (16,4,8)=512
//   blocks -> 2 blocks/CU (was 1) -> 2 waves/SIMD. Cross-round elimination
//   (R13's f32 probe moved 0.7us) re-assigns the budget: gemm ~37us at 5x its
//   ~7us issue floor because 1 wave/SIMD exposes all latency. Per-element
//   k-accumulation order and reduce8 tree UNCHANGED -> bitwise-identical
//   output (unlike a KSPLIT change). LDS 48KB/block, launch_bounds(256,2).
// reduce8, f32 readlane scan, bit-pack + expand: identical to R13.

#define T_STEPS 512
#define IN_SZ   1024
#define OUT_SZ  1024

#define BM 128
#define BN 64
#define BK 32
#define KSPLIT 8
#define KCHUNK (IN_SZ / KSPLIT)    // 128
#define NITER  (KCHUNK / BK)       // 4

typedef __attribute__((address_space(1))) const void gvoid;
typedef __attribute__((address_space(3))) void lvoid;

__global__ __launch_bounds__(256, 2) void ostl_gemm_splitk(const float* __restrict__ X,
                                                           const float* __restrict__ W,
                                                           float* __restrict__ P) {
    __shared__ float As[2][BK][BM];     // 2x16KB; A transposed [k][m]
    __shared__ float Bs[2][BK * BN];    // 2x8KB; linear [k][n]; global_load_lds dest

    const int tid = threadIdx.x;
    const int tx = tid & 15;            // output cols tx*4..+3
    const int ty = tid >> 4;            // output rows ty*8..+7
    const int n0 = blockIdx.x * BN;
    const int m0 = blockIdx.y * BM;
    const int kc = blockIdx.z;
    const int kb = kc * KCHUNK;

    const int am = tid >> 1;            // A row staged by this thread (0..127)
    const int ak = (tid & 1) * 16;      // A k-offset (0 or 16)
    const int wv = tid >> 6;            // wave 0..3
    const int ln = tid & 63;            // lane

    const float* Arow = X + (size_t)(m0 + am) * IN_SZ + kb + ak;

    float4 areg[4];

    // ---- prologue: tile 0 -> buffer 0 ----
    #pragma unroll
    for (int q = 0; q < 4; ++q)
        areg[q] = *reinterpret_cast<const float4*>(Arow + q * 4);
    #pragma unroll
    for (int j = 0; j < 2; ++j) {       // 8 instrs/block fill 32x64 B-tile
        const int i = wv * 2 + j;       // instr i covers k=4i..4i+3, n=0..63
        const float* src = W + (size_t)(kb + 4 * i + (ln >> 4)) * OUT_SZ + n0 + (ln & 15) * 4;
        __builtin_amdgcn_global_load_lds((gvoid*)src, (lvoid*)&Bs[0][i * 256], 16, 0, 0);
    }
    {
        float t[16];
        #pragma unroll
        for (int q = 0; q < 4; ++q) *reinterpret_cast<float4*>(&t[q * 4]) = areg[q];
        #pragma unroll
        for (int c = 0; c < 16; ++c) As[0][ak + c][am] = t[c];
    }
    __syncthreads();

    float acc[8][4];
    #pragma unroll
    for (int r = 0; r < 8; ++r)
        #pragma unroll
        for (int c = 0; c < 4; ++c) acc[r][c] = 0.f;

    #pragma unroll 1
    for (int it = 0; it < NITER; ++it) {
        const int cur = it & 1;
        const int nxt = cur ^ 1;

        if (it < NITER - 1) {
            const int kbase = kb + (it + 1) * BK;
            #pragma unroll
            for (int j = 0; j < 2; ++j) {
                const int i = wv * 2 + j;
                const float* src = W + (size_t)(kbase + 4 * i + (ln >> 4)) * OUT_SZ + n0 + (ln & 15) * 4;
                __builtin_amdgcn_global_load_lds((gvoid*)src, (lvoid*)&Bs[nxt][i * 256], 16, 0, 0);
            }
            #pragma unroll
            for (int q = 0; q < 4; ++q)
                areg[q] = *reinterpret_cast<const float4*>(Arow + (it + 1) * BK + q * 4);
        }

        // Same k-inner sequential fmaf order per output element as R6..R13
        // (bitwise-identical C). 32 MACs / 48 LDS bytes per k-step.
        #pragma unroll 8
        for (int k = 0; k < BK; ++k) {
            const float4 a0 = *reinterpret_cast<const float4*>(&As[cur][k][ty * 8]);
            const float4 a1 = *reinterpret_cast<const float4*>(&As[cur][k][ty * 8 + 4]);
            const float4 b0 = *reinterpret_cast<const float4*>(&Bs[cur][k * BN + tx * 4]);
            const float av[8] = {a0.x, a0.y, a0.z, a0.w, a1.x, a1.y, a1.z, a1.w};
            const float bv[4] = {b0.x, b0.y, b0.z, b0.w};
            #pragma unroll
            for (int r = 0; r < 8; ++r)
                #pragma unroll
                for (int c = 0; c < 4; ++c)
                    acc[r][c] = fmaf(av[r], bv[c], acc[r][c]);
        }

        if (it < NITER - 1) {
            float t[16];
            #pragma unroll
            for (int q = 0; q < 4; ++q) *reinterpret_cast<float4*>(&t[q * 4]) = areg[q];
            #pragma unroll
            for (int c = 0; c < 16; ++c) As[nxt][ak + c][am] = t[c];
            __syncthreads();
        }
    }

    float* Pb = P + (size_t)kc * T_STEPS * OUT_SZ + (size_t)(m0 + ty * 8) * OUT_SZ + n0;
    #pragma unroll
    for (int r = 0; r < 8; ++r) {
        *reinterpret_cast<float4*>(&Pb[(size_t)r * OUT_SZ + tx * 4]) =
            make_float4(acc[r][0], acc[r][1], acc[r][2], acc[r][3]);
    }
}

__device__ inline float4 f4add(float4 a, float4 b) {
    return make_float4(a.x + b.x, a.y + b.y, a.z + b.z, a.w + b.w);
}

// deterministic pairwise tree over the 8 k-chunk partials (exact R6..R13 kernel)
__global__ __launch_bounds__(256) void ostl_reduce8(const float* __restrict__ P,
                                                    float* __restrict__ Y) {
    const size_t idx = ((size_t)blockIdx.x * 256 + threadIdx.x) * 4;
    float4 s[8];
    #pragma unroll
    for (int c = 0; c < 8; ++c)
        s[c] = *reinterpret_cast<const float4*>(P + (size_t)c * T_STEPS * OUT_SZ + idx);
    const float4 t0 = f4add(s[0], s[1]);
    const float4 t1 = f4add(s[2], s[3]);
    const float4 t2 = f4add(s[4], s[5]);
    const float4 t3 = f4add(s[6], s[7]);
    *reinterpret_cast<float4*>(Y + idx) = f4add(f4add(t0, t1), f4add(t2, t3));
}

// Wave-per-column scan, v_readlane broadcast, bit-packed spikes, f32 chain.
// (Identical to R13, which passed with absmax 0.03125.)
__global__ __launch_bounds__(64) void ostl_scan_rl(const float* __restrict__ u0,
                                                   const float* __restrict__ Y,
                                                   unsigned* __restrict__ Bits,
                                                   float* __restrict__ u_final) {
    const int j = blockIdx.x;       // column
    const int l = threadIdx.x;      // lane

    const float sig_f = (float)0.8807970779778823;

    float u = u0[j];
    unsigned sbits = 0u;

    float ycur = Y[(size_t)l * OUT_SZ + j];            // q = 0
    #pragma unroll 1
    for (int q = 0; q < 8; ++q) {
        float ynext = 0.f;
        if (q < 7)                                     // prefetch next q-block
            ynext = Y[(size_t)((q + 1) * 64 + l) * OUT_SZ + j];
        const unsigned qbit = 1u << q;
        #pragma unroll
        for (int i = 0; i < 64; ++i) {
            const float yv = __int_as_float(
                __builtin_amdgcn_readlane(__float_as_int(ycur), i));
            const float un = fmaf(sig_f, u, yv);       // fma->cmp->cndmask chain
            const float us = un - 1.0f;
            const bool  sp = un > 1.0f;
            sbits |= (i == l && sp) ? qbit : 0u;       // off-chain
            u = sp ? us : un;
        }
        ycur = ynext;
    }
    Bits[(size_t)j * 64 + l] = sbits;                  // coalesced per wave
    if (l == 0) u_final[j] = u;
}

// Expand packed bits to float spikes (identical to R13).
__global__ __launch_bounds__(256) void ostl_expand(const unsigned* __restrict__ Bits,
                                                   float* __restrict__ S) {
    const int t = blockIdx.x;          // 0..511
    const int c = t & 63;
    const int q = t >> 6;
    const int j4 = threadIdx.x * 4;
    float4 v;
    v.x = (float)((Bits[(size_t)(j4 + 0) * 64 + c] >> q) & 1u);
    v.y = (float)((Bits[(size_t)(j4 + 1) * 64 + c] >> q) & 1u);
    v.z = (float)((Bits[(size_t)(j4 + 2) * 64 + c] >> q) & 1u);
    v.w = (float)((Bits[(size_t)(j4 + 3) * 64 + c] >> q) & 1u);
    *reinterpret_cast<float4*>(&S[(size_t)t * OUT_SZ + j4]) = v;
}

extern "C" void kernel_launch(void* const* d_in, const int* in_sizes, int n_in,
                              void* d_out, int out_size, void* d_ws, size_t ws_size,
                              hipStream_t stream) {
    const float* x_seq  = (const float*)d_in[0];   // [512,1024]
    const float* kernel = (const float*)d_in[1];   // [1024,1024]
    const float* u0     = (const float*)d_in[2];   // [1024]
    // d_in[3] = E0: unused in the primal path.

    float* out      = (float*)d_out;
    float* spikes   = out;                               // [512,1024]
    float* u_final  = out + (size_t)T_STEPS * OUT_SZ;    // [1024]

    float*    partials = (float*)d_ws;                   // 8 x [512,1024] = 16 MB
    float*    yb       = partials + (size_t)KSPLIT * T_STEPS * OUT_SZ;  // 2 MB
    unsigned* bits     = (unsigned*)(yb + (size_t)T_STEPS * OUT_SZ);    // 256 KB

    dim3 ggrid(OUT_SZ / BN, T_STEPS / BM, KSPLIT);       // (16, 4, 8) = 512 blocks
    ostl_gemm_splitk<<<ggrid, dim3(256), 0, stream>>>(x_seq, kernel, partials);

    ostl_reduce8<<<dim3((T_STEPS * OUT_SZ / 4) / 256), dim3(256), 0, stream>>>(partials, yb);

    ostl_scan_rl<<<dim3(OUT_SZ), dim3(64), 0, stream>>>(u0, yb, bits, u_final);

    ostl_expand<<<dim3(T_STEPS), dim3(256), 0, stream>>>(bits, spikes);
}